// Round 9
// baseline (162.107 us; speedup 1.0000x reference)
//
#include <hip/hip_runtime.h>
#include <math.h>

// PAM module: B=8, C=64, CQ=8, N=2048
// out[b,c,i] = gamma * sum_j softmax_j(q[i,:]·k[:,j]) * v[c,j] + x[b,c,i]
//
// ws layouts (bf16), in MFMA-fragment order so attn loads are contiguous:
//  Q[b][ib(128)][half(2)][li(16)][e(8)]            (32768/batch)
//  K[b][t(32)][f(4)][half(2)][li(16)][e(8)]        (32768/batch)  j=t*64+f*16+li
//  V[b][t(32)][jc(2)][cb(4)][li(16)][g(4)][e(8)]   (131072/batch) j=t*64+jc*32+g*8+e, c=cb*16+li
//
// DIAGNOSTIC ROUND: REPQ/REPA internal repetitions (output-invariant) inflate
// dispatch durations past the harness's ~40us fills so both kernels surface
// in rocprof top-5 with full counters. Strip reps next round.

#define NB  8
#define NC  64
#define NN  2048
#define L2E 1.44269504088896340736f
#define THR 8.0f        // defer-max threshold (exp2 domain)
#define SPW 72          // sP pitch in ushorts per row (144B)
#define MST 36          // merge acc stride (floats per lane)
#define REPQ 12
#define REPA 10

typedef float f32x4 __attribute__((ext_vector_type(4)));
typedef __bf16 bf16x8 __attribute__((ext_vector_type(8)));
typedef __bf16 bf16x4 __attribute__((ext_vector_type(4)));
typedef unsigned short ushort_t;
typedef unsigned short us4 __attribute__((ext_vector_type(4)));

__device__ __forceinline__ unsigned short f2bf(float f) {
    unsigned u = __float_as_uint(f);
    u += 0x7fffu + ((u >> 16) & 1u);          // RNE
    return (unsigned short)(u >> 16);
}
__device__ __forceinline__ float bf2f(unsigned short h) {
    return __uint_as_float(((unsigned)h) << 16);
}

// ---------------- QKV projection v4 (+rep instrumentation) ----------------
__global__ __launch_bounds__(256) void qkv_kernel(
    const float* __restrict__ x,
    const float* __restrict__ Wq, const float* __restrict__ bq,
    const float* __restrict__ Wk, const float* __restrict__ bk,
    const float* __restrict__ Wv, const float* __restrict__ bv,
    ushort_t* __restrict__ Qws, ushort_t* __restrict__ Kws,
    ushort_t* __restrict__ Vws)
{
    __shared__ float sWg[64][20];
    __shared__ float sB[16];
    __shared__ float sX[64][64];

    const int tid = threadIdx.x;
    const unsigned blk = blockIdx.x;
    const int b = blk & 7;
    const unsigned rest = blk >> 3;
    const unsigned pc = rest / 5u;
    const int og = (int)(rest - pc * 5u);
    const int n0 = (int)pc * 64;
    const int obase = og * 16;

    for (int idx = tid; idx < 1024; idx += 256) {
        const int o = idx >> 6;
        const int c = idx & 63;
        const int oo = obase + o;
        float w;
        if (oo < 8)       w = Wq[oo * NC + c] * L2E;
        else if (oo < 16) w = Wk[(oo - 8) * NC + c];
        else              w = Wv[(oo - 16) * NC + c];
        sWg[c][o] = w;
    }
    if (tid < 16) {
        const int oo = obase + tid;
        float v;
        if (oo < 8)       v = bq[oo] * L2E;
        else if (oo < 16) v = bk[oo - 8];
        else              v = bv[oo - 16];
        sB[tid] = v;
    }

    const int lanepx = tid & 63;
    const int wv = tid >> 6;
    const int n = n0 + lanepx;
    const int t  = n >> 6;
    const int f  = (n >> 4) & 3;
    const int li = n & 15;

    for (int rp = 0; rp < REPQ; ++rp) {
        __syncthreads();
        {
            const float* xg = x + (size_t)b * NC * NN + n0;
            for (int idx = tid; idx < 4096; idx += 256) {
                const int c = idx >> 6, px = idx & 63;
                sX[c][px] = xg[(size_t)c * NN + px];
            }
        }
        __syncthreads();

        f32x4 acc = { sB[wv*4+0], sB[wv*4+1], sB[wv*4+2], sB[wv*4+3] };
        #pragma unroll
        for (int ch = 0; ch < 64; ch++) {
            const float xv = sX[ch][lanepx];
            const f32x4 w = *(const f32x4*)&sWg[ch][wv * 4];
            acc[0] = fmaf(w[0], xv, acc[0]);
            acc[1] = fmaf(w[1], xv, acc[1]);
            acc[2] = fmaf(w[2], xv, acc[2]);
            acc[3] = fmaf(w[3], xv, acc[3]);
        }

        if (og == 0) {
            us4 hi, lo;
            #pragma unroll
            for (int e = 0; e < 4; e++) {
                const unsigned short h = f2bf(acc[e]);
                hi[e] = h;
                lo[e] = f2bf(acc[e] - bf2f(h));
            }
            if (wv < 2) {
                const size_t a = (size_t)b * 32768 + (size_t)(n >> 4) * 256
                               + (size_t)li * 8 + wv * 4;
                *(us4*)(Qws + a)       = hi;
                *(us4*)(Qws + a + 128) = lo;
            } else {
                const size_t a = (size_t)b * 32768 + (size_t)t * 1024
                               + (size_t)f * 256 + (size_t)li * 8 + (wv - 2) * 4;
                *(us4*)(Kws + a)       = hi;
                *(us4*)(Kws + a + 128) = lo;
            }
        } else {
            const int jc = (n >> 5) & 1;
            const int gg = (n >> 3) & 3;
            const int e8 = n & 7;
            const int cb = og - 1;
            const size_t base = (size_t)b * 131072 + (size_t)t * 4096
                              + (size_t)jc * 2048 + (size_t)cb * 512
                              + (size_t)gg * 8 + e8;
            #pragma unroll
            for (int e = 0; e < 4; e++)
                Vws[base + (size_t)(wv * 4 + e) * 32] = f2bf(acc[e]);
        }
    }
}

// ---------------- fused flash attention v9 --------------------------------
// 256 blocks = 8 b x 32 rb (1/CU); 512 threads = 8 waves = 2 rg x 4 jq.
// Wave: 32 rows (2 i-blocks) x 512 j (8 steps of 64). launch_bounds(512,2)
// -> 256-VGPR budget, no spills (v8's bug). Fragment-order K/V from L2,
// K prefetch 1 step, per-wave P in LDS, defer-max, 4-way merge per rg.
__global__ __launch_bounds__(512, 2) void attn_kernel(
    const ushort_t* __restrict__ Qg, const ushort_t* __restrict__ Kg,
    const ushort_t* __restrict__ Vg, const float* __restrict__ x,
    const float* __restrict__ gamma, float* __restrict__ out)
{
    __shared__ __align__(16) char smem[75776];
    ushort_t* sP    = (ushort_t*)smem;         // [8 waves][32 rows][SPW]
    float*    sMacc = (float*)smem;            // [8*64 lanes][MST]
    float*    sMml  = (float*)smem + 18432;    // [8*32 rows][2]

    const int tid  = threadIdx.x;
    const int w    = tid >> 6;          // 0..7
    const int rg   = w >> 2;            // row-group 0..1
    const int jq   = w & 3;             // j-quarter 0..3
    const int lane = tid & 63;
    const int li   = lane & 15;
    const int g    = lane >> 4;
    const int b    = blockIdx.x & 7;    // batch -> XCD
    const int rb   = blockIdx.x >> 3;   // 0..31
    const int i0   = rb * 64 + rg * 32;

    const ushort_t* Kb = Kg + (size_t)b * 32768;
    const ushort_t* Vb = Vg + (size_t)b * 131072;

    const int ib0 = rb * 4 + rg * 2;
    bf16x8 qf0 = *(const bf16x8*)(Qg + (size_t)b * 32768 + (size_t)ib0 * 256
                                  + (size_t)(g & 1) * 128 + (size_t)li * 8);
    bf16x8 qf1 = *(const bf16x8*)(Qg + (size_t)b * 32768 + (size_t)(ib0 + 1) * 256
                                  + (size_t)(g & 1) * 128 + (size_t)li * 8);

    ushort_t* sPw = sP + (size_t)w * 32 * SPW;

    float m0 = -INFINITY, m1 = -INFINITY, l0 = 0.f, l1 = 0.f;
    f32x4 acc0[4], acc1[4];
    #pragma unroll
    for (int cb = 0; cb < 4; cb++) {
        acc0[cb] = (f32x4){0.f,0.f,0.f,0.f};
        acc1[cb] = (f32x4){0.f,0.f,0.f,0.f};
    }
    const f32x4 zero4 = {0.f,0.f,0.f,0.f};

    const size_t koff = (size_t)(g >> 1) * 128 + (size_t)li * 8;
    const size_t voff = (size_t)li * 32 + (size_t)g * 8;

    for (int rp = 0; rp < REPA; ++rp) {
        bf16x8 kc[4];
        #pragma unroll
        for (int f = 0; f < 4; f++)
            kc[f] = *(const bf16x8*)(Kb + (size_t)(jq * 8) * 1024 + (size_t)f * 256 + koff);

        for (int t = 0; t < 8; ++t) {
            const int tt = jq * 8 + t;

            // V jc=0 issued at step top
            bf16x8 vc0[4];
            #pragma unroll
            for (int cb = 0; cb < 4; cb++)
                vc0[cb] = *(const bf16x8*)(Vb + (size_t)tt * 4096 + (size_t)cb * 512 + voff);

            // ---- QK ib0 ----
            f32x4 e[4];
            __builtin_amdgcn_s_setprio(1);
            #pragma unroll
            for (int f = 0; f < 4; f++)
                e[f] = __builtin_amdgcn_mfma_f32_16x16x32_bf16(kc[f], qf0, zero4, 0, 0, 0);
            __builtin_amdgcn_s_setprio(0);

            // V jc=1 issued mid-step
            bf16x8 vc1[4];
            #pragma unroll
            for (int cb = 0; cb < 4; cb++)
                vc1[cb] = *(const bf16x8*)(Vb + (size_t)tt * 4096 + 2048 + (size_t)cb * 512 + voff);

            // ---- softmax ib0 (defer-max) ----
            {
                float pmax = fmaxf(fmaxf(fmaxf(e[0][0], e[0][1]), fmaxf(e[0][2], e[0][3])),
                             fmaxf(fmaxf(fmaxf(e[1][0], e[1][1]), fmaxf(e[1][2], e[1][3])),
                             fmaxf(fmaxf(fmaxf(e[2][0], e[2][1]), fmaxf(e[2][2], e[2][3])),
                                   fmaxf(fmaxf(e[3][0], e[3][1]), fmaxf(e[3][2], e[3][3])))));
                if (!__all(pmax <= m0 + THR)) {
                    float mx = pmax;
                    mx = fmaxf(mx, __shfl_xor(mx, 16));
                    mx = fmaxf(mx, __shfl_xor(mx, 32));
                    const float nm = fmaxf(m0, mx);
                    const float sc = __builtin_amdgcn_exp2f(m0 - nm);
                    m0 = nm; l0 *= sc;
                    #pragma unroll
                    for (int cb = 0; cb < 4; cb++) {
                        acc0[cb][0]*=sc; acc0[cb][1]*=sc; acc0[cb][2]*=sc; acc0[cb][3]*=sc;
                    }
                }
                #pragma unroll
                for (int f = 0; f < 4; f++) {
                    const float p0 = __builtin_amdgcn_exp2f(e[f][0] - m0);
                    const float p1 = __builtin_amdgcn_exp2f(e[f][1] - m0);
                    const float p2 = __builtin_amdgcn_exp2f(e[f][2] - m0);
                    const float p3 = __builtin_amdgcn_exp2f(e[f][3] - m0);
                    l0 += (p0 + p1) + (p2 + p3);
                    const bf16x4 pk = { (__bf16)p0, (__bf16)p1, (__bf16)p2, (__bf16)p3 };
                    *(bf16x4*)(sPw + (size_t)li * SPW + f * 16 + g * 4) = pk;
                }
            }

            // ---- QK ib1 ----
            __builtin_amdgcn_s_setprio(1);
            #pragma unroll
            for (int f = 0; f < 4; f++)
                e[f] = __builtin_amdgcn_mfma_f32_16x16x32_bf16(kc[f], qf1, zero4, 0, 0, 0);
            __builtin_amdgcn_s_setprio(0);

            // prefetch next step's K
            if (t < 7) {
                #pragma unroll
                for (int f = 0; f < 4; f++)
                    kc[f] = *(const bf16x8*)(Kb + (size_t)(tt + 1) * 1024
                                             + (size_t)f * 256 + koff);
            }

            // ---- softmax ib1 ----
            {
                float pmax = fmaxf(fmaxf(fmaxf(e[0][0], e[0][1]), fmaxf(e[0][2], e[0][3])),
                             fmaxf(fmaxf(fmaxf(e[1][0], e[1][1]), fmaxf(e[1][2], e[1][3])),
                             fmaxf(fmaxf(fmaxf(e[2][0], e[2][1]), fmaxf(e[2][2], e[2][3])),
                                   fmaxf(fmaxf(e[3][0], e[3][1]), fmaxf(e[3][2], e[3][3])))));
                if (!__all(pmax <= m1 + THR)) {
                    float mx = pmax;
                    mx = fmaxf(mx, __shfl_xor(mx, 16));
                    mx = fmaxf(mx, __shfl_xor(mx, 32));
                    const float nm = fmaxf(m1, mx);
                    const float sc = __builtin_amdgcn_exp2f(m1 - nm);
                    m1 = nm; l1 *= sc;
                    #pragma unroll
                    for (int cb = 0; cb < 4; cb++) {
                        acc1[cb][0]*=sc; acc1[cb][1]*=sc; acc1[cb][2]*=sc; acc1[cb][3]*=sc;
                    }
                }
                #pragma unroll
                for (int f = 0; f < 4; f++) {
                    const float p0 = __builtin_amdgcn_exp2f(e[f][0] - m1);
                    const float p1 = __builtin_amdgcn_exp2f(e[f][1] - m1);
                    const float p2 = __builtin_amdgcn_exp2f(e[f][2] - m1);
                    const float p3 = __builtin_amdgcn_exp2f(e[f][3] - m1);
                    l1 += (p0 + p1) + (p2 + p3);
                    const bf16x4 pk = { (__bf16)p0, (__bf16)p1, (__bf16)p2, (__bf16)p3 };
                    *(bf16x4*)(sPw + (size_t)(16 + li) * SPW + f * 16 + g * 4) = pk;
                }
            }

            // ---- PV (same-wave LDS reads, no barrier) ----
            __builtin_amdgcn_s_setprio(1);
            {
                const bf16x8 pf0 = *(const bf16x8*)(sPw + (size_t)li * SPW + g * 8);
                const bf16x8 pf1 = *(const bf16x8*)(sPw + (size_t)(16 + li) * SPW + g * 8);
                #pragma unroll
                for (int cb = 0; cb < 4; cb++) {
                    acc0[cb] = __builtin_amdgcn_mfma_f32_16x16x32_bf16(vc0[cb], pf0, acc0[cb], 0, 0, 0);
                    acc1[cb] = __builtin_amdgcn_mfma_f32_16x16x32_bf16(vc0[cb], pf1, acc1[cb], 0, 0, 0);
                }
            }
            {
                const bf16x8 pf0 = *(const bf16x8*)(sPw + (size_t)li * SPW + 32 + g * 8);
                const bf16x8 pf1 = *(const bf16x8*)(sPw + (size_t)(16 + li) * SPW + 32 + g * 8);
                #pragma unroll
                for (int cb = 0; cb < 4; cb++) {
                    acc0[cb] = __builtin_amdgcn_mfma_f32_16x16x32_bf16(vc1[cb], pf0, acc0[cb], 0, 0, 0);
                    acc1[cb] = __builtin_amdgcn_mfma_f32_16x16x32_bf16(vc1[cb], pf1, acc1[cb], 0, 0, 0);
                }
            }
            __builtin_amdgcn_s_setprio(0);
        }
    }

    // row-total l across the 4 g-lanes
    l0 += __shfl_xor(l0, 16); l0 += __shfl_xor(l0, 32);
    l1 += __shfl_xor(l1, 16); l1 += __shfl_xor(l1, 32);

    // ---- per-rg 4-way merge ----
    __syncthreads();   // everyone done with sP
    {
        float* ap = sMacc + (size_t)(w * 64 + lane) * MST;
        #pragma unroll
        for (int cb = 0; cb < 4; cb++) {
            *(f32x4*)(ap + cb * 4)      = acc0[cb];
            *(f32x4*)(ap + 16 + cb * 4) = acc1[cb];
        }
        if (g == 0) {
            float* p0 = sMml + (size_t)(w * 32 + li) * 2;
            p0[0] = m0; p0[1] = l0;
            float* p1 = sMml + (size_t)(w * 32 + 16 + li) * 2;
            p1[0] = m1; p1[1] = l1;
        }
    }
    __syncthreads();

    {
        const int r = lane & 31;
        const float gmv = gamma[0];
        #pragma unroll
        for (int u = 0; u < 2; u++) {
            const int cq   = jq * 4 + (lane >> 5) * 2 + u;   // 0..15
            const int g_s  = cq & 3;
            const int cb_s = cq >> 2;
            const int ib_s = r >> 4;
            const int li_s = r & 15;
            const int srcln = g_s * 16 + li_s;
            const int aidx  = ib_s * 16 + cb_s * 4;

            float mv[4], lv[4];
            f32x4 av[4];
            #pragma unroll
            for (int q = 0; q < 4; q++) {
                const int w2 = rg * 4 + q;
                const float* mlp = sMml + (size_t)(w2 * 32 + r) * 2;
                mv[q] = mlp[0]; lv[q] = mlp[1];
                av[q] = *(const f32x4*)(sMacc + (size_t)(w2 * 64 + srcln) * MST + aidx);
            }
            const float M = fmaxf(fmaxf(mv[0], mv[1]), fmaxf(mv[2], mv[3]));
            float L = 0.f;
            float num0 = 0.f, num1 = 0.f, num2 = 0.f, num3 = 0.f;
            #pragma unroll
            for (int q = 0; q < 4; q++) {
                const float s = __builtin_amdgcn_exp2f(mv[q] - M);
                L = fmaf(s, lv[q], L);
                num0 = fmaf(s, av[q][0], num0);
                num1 = fmaf(s, av[q][1], num1);
                num2 = fmaf(s, av[q][2], num2);
                num3 = fmaf(s, av[q][3], num3);
            }
            const float inv = 1.0f / L;
            const size_t gb = (size_t)b * NC * NN + i0 + r;
            const size_t c0 = (size_t)cq * 4;
            out[gb + (c0 + 0) * NN] = fmaf(gmv, num0 * inv, x[gb + (c0 + 0) * NN]);
            out[gb + (c0 + 1) * NN] = fmaf(gmv, num1 * inv, x[gb + (c0 + 1) * NN]);
            out[gb + (c0 + 2) * NN] = fmaf(gmv, num2 * inv, x[gb + (c0 + 2) * NN]);
            out[gb + (c0 + 3) * NN] = fmaf(gmv, num3 * inv, x[gb + (c0 + 3) * NN]);
        }
    }
}

extern "C" void kernel_launch(void* const* d_in, const int* in_sizes, int n_in,
                              void* d_out, int out_size, void* d_ws, size_t ws_size,
                              hipStream_t stream) {
    const float* x     = (const float*)d_in[0];
    const float* Wq    = (const float*)d_in[1];
    const float* bq    = (const float*)d_in[2];
    const float* Wk    = (const float*)d_in[3];
    const float* bk    = (const float*)d_in[4];
    const float* Wv    = (const float*)d_in[5];
    const float* bv    = (const float*)d_in[6];
    const float* gamma = (const float*)d_in[7];
    float* out = (float*)d_out;

    // ws (ushorts): Q 8*32768 | K 8*32768 | V 8*131072  (3 MB total)
    ushort_t* Qws = (ushort_t*)d_ws;
    ushort_t* Kws = Qws + (size_t)NB * 32768;
    ushort_t* Vws = Kws + (size_t)NB * 32768;

    qkv_kernel<<<1280, 256, 0, stream>>>(x, Wq, bq, Wk, bk, Wv, bv, Qws, Kws, Vws);
    attn_kernel<<<256, 512, 0, stream>>>(Qws, Kws, Vws, x, gamma, out);
}

// Round 10
// 26.855 us; speedup vs baseline: 6.0364x; 6.0364x over previous
//
#include <hip/hip_runtime.h>
#include <math.h>

// PAM module: B=8, C=64, CQ=8, N=2048
// out[b,c,i] = gamma * sum_j softmax_j(q[i,:]·k[:,j]) * v[c,j] + x[b,c,i]
//
// ws layouts (bf16), in MFMA-fragment order so attn loads are contiguous:
//  Q[b][ib(128)][half(2)][li(16)][e(8)]            (32768/batch)
//  K[b][t(32)][f(4)][half(2)][li(16)][e(8)]        (32768/batch)  j=t*64+f*16+li
//  V[b][t(32)][jc(2)][cb(4)][li(16)][g(4)][e(8)]   (131072/batch) j=t*64+jc*32+g*8+e, c=cb*16+li

#define NB  8
#define NC  64
#define NN  2048
#define L2E 1.44269504088896340736f
#define THR 8.0f        // defer-max threshold (exp2 domain)
#define SPW 72          // sP pitch in ushorts per row (144B)
#define MST 36          // merge acc stride (floats per lane)

typedef float f32x4 __attribute__((ext_vector_type(4)));
typedef __bf16 bf16x8 __attribute__((ext_vector_type(8)));
typedef __bf16 bf16x4 __attribute__((ext_vector_type(4)));
typedef unsigned short ushort_t;
typedef unsigned short us4 __attribute__((ext_vector_type(4)));

__device__ __forceinline__ unsigned short f2bf(float f) {
    unsigned u = __float_as_uint(f);
    u += 0x7fffu + ((u >> 16) & 1u);          // RNE
    return (unsigned short)(u >> 16);
}
__device__ __forceinline__ float bf2f(unsigned short h) {
    return __uint_as_float(((unsigned)h) << 16);
}

// ---------------- QKV projection v4 (clean, no reps) ----------------
__global__ __launch_bounds__(256) void qkv_kernel(
    const float* __restrict__ x,
    const float* __restrict__ Wq, const float* __restrict__ bq,
    const float* __restrict__ Wk, const float* __restrict__ bk,
    const float* __restrict__ Wv, const float* __restrict__ bv,
    ushort_t* __restrict__ Qws, ushort_t* __restrict__ Kws,
    ushort_t* __restrict__ Vws)
{
    __shared__ float sWg[64][20];
    __shared__ float sB[16];
    __shared__ float sX[64][64];

    const int tid = threadIdx.x;
    const unsigned blk = blockIdx.x;
    const int b = blk & 7;
    const unsigned rest = blk >> 3;
    const unsigned pc = rest / 5u;
    const int og = (int)(rest - pc * 5u);
    const int n0 = (int)pc * 64;
    const int obase = og * 16;

    for (int idx = tid; idx < 1024; idx += 256) {
        const int o = idx >> 6;
        const int c = idx & 63;
        const int oo = obase + o;
        float w;
        if (oo < 8)       w = Wq[oo * NC + c] * L2E;
        else if (oo < 16) w = Wk[(oo - 8) * NC + c];
        else              w = Wv[(oo - 16) * NC + c];
        sWg[c][o] = w;
    }
    if (tid < 16) {
        const int oo = obase + tid;
        float v;
        if (oo < 8)       v = bq[oo] * L2E;
        else if (oo < 16) v = bk[oo - 8];
        else              v = bv[oo - 16];
        sB[tid] = v;
    }
    {
        const float* xg = x + (size_t)b * NC * NN + n0;
        for (int idx = tid; idx < 4096; idx += 256) {
            const int c = idx >> 6, px = idx & 63;
            sX[c][px] = xg[(size_t)c * NN + px];
        }
    }
    __syncthreads();

    const int lanepx = tid & 63;
    const int wv = tid >> 6;

    f32x4 acc = { sB[wv*4+0], sB[wv*4+1], sB[wv*4+2], sB[wv*4+3] };
    #pragma unroll
    for (int ch = 0; ch < 64; ch++) {
        const float xv = sX[ch][lanepx];
        const f32x4 w = *(const f32x4*)&sWg[ch][wv * 4];
        acc[0] = fmaf(w[0], xv, acc[0]);
        acc[1] = fmaf(w[1], xv, acc[1]);
        acc[2] = fmaf(w[2], xv, acc[2]);
        acc[3] = fmaf(w[3], xv, acc[3]);
    }

    const int n = n0 + lanepx;
    const int t  = n >> 6;
    const int f  = (n >> 4) & 3;
    const int li = n & 15;

    if (og == 0) {
        us4 hi, lo;
        #pragma unroll
        for (int e = 0; e < 4; e++) {
            const unsigned short h = f2bf(acc[e]);
            hi[e] = h;
            lo[e] = f2bf(acc[e] - bf2f(h));
        }
        if (wv < 2) {
            const size_t a = (size_t)b * 32768 + (size_t)(n >> 4) * 256
                           + (size_t)li * 8 + wv * 4;
            *(us4*)(Qws + a)       = hi;
            *(us4*)(Qws + a + 128) = lo;
        } else {
            const size_t a = (size_t)b * 32768 + (size_t)t * 1024
                           + (size_t)f * 256 + (size_t)li * 8 + (wv - 2) * 4;
            *(us4*)(Kws + a)       = hi;
            *(us4*)(Kws + a + 128) = lo;
        }
    } else {
        const int jc = (n >> 5) & 1;
        const int gg = (n >> 3) & 3;
        const int e8 = n & 7;
        const int cb = og - 1;
        const size_t base = (size_t)b * 131072 + (size_t)t * 4096
                          + (size_t)jc * 2048 + (size_t)cb * 512
                          + (size_t)gg * 8 + e8;
        #pragma unroll
        for (int e = 0; e < 4; e++)
            Vws[base + (size_t)(wv * 4 + e) * 32] = f2bf(acc[e]);
    }
}

// ---------------- fused flash attention v10 -------------------------------
// 512 blocks = 8 b x 64 rb (2 blocks/CU); 512 threads = 8 waves = 8 j-eighths.
// Wave: 32 rows (2 i-blocks) x 256 j (4 rolled steps of 64). v9's register
// structure (VGPR ~100 -> 16 waves/CU with LDS 75776x2 = 151.5KB/CU).
// Fragment-order K/V from L2, K prefetch, per-wave P in LDS, defer-max,
// 8-way merge epilogue (v8's proven indexing).
__global__ __launch_bounds__(512, 2) void attn_kernel(
    const ushort_t* __restrict__ Qg, const ushort_t* __restrict__ Kg,
    const ushort_t* __restrict__ Vg, const float* __restrict__ x,
    const float* __restrict__ gamma, float* __restrict__ out)
{
    __shared__ __align__(16) char smem[75776];
    ushort_t* sP    = (ushort_t*)smem;         // [8 waves][32 rows][SPW]
    float*    sMacc = (float*)smem;            // [8*64 lanes][MST]
    float*    sMml  = (float*)smem + 18432;    // [8*32 rows][2]

    const int tid  = threadIdx.x;
    const int w    = tid >> 6;          // j-eighth 0..7
    const int lane = tid & 63;
    const int li   = lane & 15;
    const int g    = lane >> 4;
    const int b    = blockIdx.x & 7;    // batch -> XCD
    const int rb   = blockIdx.x >> 3;   // 0..63
    const int i0   = rb * 32;

    const ushort_t* Kb = Kg + (size_t)b * 32768;
    const ushort_t* Vb = Vg + (size_t)b * 131072;

    const int ib0 = rb * 2;
    bf16x8 qf0 = *(const bf16x8*)(Qg + (size_t)b * 32768 + (size_t)ib0 * 256
                                  + (size_t)(g & 1) * 128 + (size_t)li * 8);
    bf16x8 qf1 = *(const bf16x8*)(Qg + (size_t)b * 32768 + (size_t)(ib0 + 1) * 256
                                  + (size_t)(g & 1) * 128 + (size_t)li * 8);

    ushort_t* sPw = sP + (size_t)w * 32 * SPW;

    float m0 = -INFINITY, m1 = -INFINITY, l0 = 0.f, l1 = 0.f;
    f32x4 acc0[4], acc1[4];
    #pragma unroll
    for (int cb = 0; cb < 4; cb++) {
        acc0[cb] = (f32x4){0.f,0.f,0.f,0.f};
        acc1[cb] = (f32x4){0.f,0.f,0.f,0.f};
    }
    const f32x4 zero4 = {0.f,0.f,0.f,0.f};

    const size_t koff = (size_t)(g >> 1) * 128 + (size_t)li * 8;
    const size_t voff = (size_t)li * 32 + (size_t)g * 8;

    bf16x8 kc[4];
    #pragma unroll
    for (int f = 0; f < 4; f++)
        kc[f] = *(const bf16x8*)(Kb + (size_t)(w * 4) * 1024 + (size_t)f * 256 + koff);

    for (int t = 0; t < 4; ++t) {       // rolled on purpose (v8 unrolled -> spills)
        const int tt = w * 4 + t;

        // V jc=0 issued at step top
        bf16x8 vc0[4];
        #pragma unroll
        for (int cb = 0; cb < 4; cb++)
            vc0[cb] = *(const bf16x8*)(Vb + (size_t)tt * 4096 + (size_t)cb * 512 + voff);

        // ---- QK ib0 ----
        f32x4 e[4];
        __builtin_amdgcn_s_setprio(1);
        #pragma unroll
        for (int f = 0; f < 4; f++)
            e[f] = __builtin_amdgcn_mfma_f32_16x16x32_bf16(kc[f], qf0, zero4, 0, 0, 0);
        __builtin_amdgcn_s_setprio(0);

        // V jc=1 issued mid-step
        bf16x8 vc1[4];
        #pragma unroll
        for (int cb = 0; cb < 4; cb++)
            vc1[cb] = *(const bf16x8*)(Vb + (size_t)tt * 4096 + 2048 + (size_t)cb * 512 + voff);

        // ---- softmax ib0 (defer-max) ----
        {
            float pmax = fmaxf(fmaxf(fmaxf(e[0][0], e[0][1]), fmaxf(e[0][2], e[0][3])),
                         fmaxf(fmaxf(fmaxf(e[1][0], e[1][1]), fmaxf(e[1][2], e[1][3])),
                         fmaxf(fmaxf(fmaxf(e[2][0], e[2][1]), fmaxf(e[2][2], e[2][3])),
                               fmaxf(fmaxf(e[3][0], e[3][1]), fmaxf(e[3][2], e[3][3])))));
            if (!__all(pmax <= m0 + THR)) {
                float mx = pmax;
                mx = fmaxf(mx, __shfl_xor(mx, 16));
                mx = fmaxf(mx, __shfl_xor(mx, 32));
                const float nm = fmaxf(m0, mx);
                const float sc = __builtin_amdgcn_exp2f(m0 - nm);
                m0 = nm; l0 *= sc;
                #pragma unroll
                for (int cb = 0; cb < 4; cb++) {
                    acc0[cb][0]*=sc; acc0[cb][1]*=sc; acc0[cb][2]*=sc; acc0[cb][3]*=sc;
                }
            }
            #pragma unroll
            for (int f = 0; f < 4; f++) {
                const float p0 = __builtin_amdgcn_exp2f(e[f][0] - m0);
                const float p1 = __builtin_amdgcn_exp2f(e[f][1] - m0);
                const float p2 = __builtin_amdgcn_exp2f(e[f][2] - m0);
                const float p3 = __builtin_amdgcn_exp2f(e[f][3] - m0);
                l0 += (p0 + p1) + (p2 + p3);
                const bf16x4 pk = { (__bf16)p0, (__bf16)p1, (__bf16)p2, (__bf16)p3 };
                *(bf16x4*)(sPw + (size_t)li * SPW + f * 16 + g * 4) = pk;
            }
        }

        // ---- QK ib1 ----
        __builtin_amdgcn_s_setprio(1);
        #pragma unroll
        for (int f = 0; f < 4; f++)
            e[f] = __builtin_amdgcn_mfma_f32_16x16x32_bf16(kc[f], qf1, zero4, 0, 0, 0);
        __builtin_amdgcn_s_setprio(0);

        // prefetch next step's K
        if (t < 3) {
            #pragma unroll
            for (int f = 0; f < 4; f++)
                kc[f] = *(const bf16x8*)(Kb + (size_t)(tt + 1) * 1024
                                         + (size_t)f * 256 + koff);
        }

        // ---- softmax ib1 ----
        {
            float pmax = fmaxf(fmaxf(fmaxf(e[0][0], e[0][1]), fmaxf(e[0][2], e[0][3])),
                         fmaxf(fmaxf(fmaxf(e[1][0], e[1][1]), fmaxf(e[1][2], e[1][3])),
                         fmaxf(fmaxf(fmaxf(e[2][0], e[2][1]), fmaxf(e[2][2], e[2][3])),
                               fmaxf(fmaxf(e[3][0], e[3][1]), fmaxf(e[3][2], e[3][3])))));
            if (!__all(pmax <= m1 + THR)) {
                float mx = pmax;
                mx = fmaxf(mx, __shfl_xor(mx, 16));
                mx = fmaxf(mx, __shfl_xor(mx, 32));
                const float nm = fmaxf(m1, mx);
                const float sc = __builtin_amdgcn_exp2f(m1 - nm);
                m1 = nm; l1 *= sc;
                #pragma unroll
                for (int cb = 0; cb < 4; cb++) {
                    acc1[cb][0]*=sc; acc1[cb][1]*=sc; acc1[cb][2]*=sc; acc1[cb][3]*=sc;
                }
            }
            #pragma unroll
            for (int f = 0; f < 4; f++) {
                const float p0 = __builtin_amdgcn_exp2f(e[f][0] - m1);
                const float p1 = __builtin_amdgcn_exp2f(e[f][1] - m1);
                const float p2 = __builtin_amdgcn_exp2f(e[f][2] - m1);
                const float p3 = __builtin_amdgcn_exp2f(e[f][3] - m1);
                l1 += (p0 + p1) + (p2 + p3);
                const bf16x4 pk = { (__bf16)p0, (__bf16)p1, (__bf16)p2, (__bf16)p3 };
                *(bf16x4*)(sPw + (size_t)(16 + li) * SPW + f * 16 + g * 4) = pk;
            }
        }

        // ---- PV (same-wave LDS reads, no barrier) ----
        __builtin_amdgcn_s_setprio(1);
        {
            const bf16x8 pf0 = *(const bf16x8*)(sPw + (size_t)li * SPW + g * 8);
            const bf16x8 pf1 = *(const bf16x8*)(sPw + (size_t)(16 + li) * SPW + g * 8);
            #pragma unroll
            for (int cb = 0; cb < 4; cb++) {
                acc0[cb] = __builtin_amdgcn_mfma_f32_16x16x32_bf16(vc0[cb], pf0, acc0[cb], 0, 0, 0);
                acc1[cb] = __builtin_amdgcn_mfma_f32_16x16x32_bf16(vc0[cb], pf1, acc1[cb], 0, 0, 0);
            }
        }
        {
            const bf16x8 pf0 = *(const bf16x8*)(sPw + (size_t)li * SPW + 32 + g * 8);
            const bf16x8 pf1 = *(const bf16x8*)(sPw + (size_t)(16 + li) * SPW + 32 + g * 8);
            #pragma unroll
            for (int cb = 0; cb < 4; cb++) {
                acc0[cb] = __builtin_amdgcn_mfma_f32_16x16x32_bf16(vc1[cb], pf0, acc0[cb], 0, 0, 0);
                acc1[cb] = __builtin_amdgcn_mfma_f32_16x16x32_bf16(vc1[cb], pf1, acc1[cb], 0, 0, 0);
            }
        }
        __builtin_amdgcn_s_setprio(0);
    }

    // row-total l across the 4 g-lanes
    l0 += __shfl_xor(l0, 16); l0 += __shfl_xor(l0, 32);
    l1 += __shfl_xor(l1, 16); l1 += __shfl_xor(l1, 32);

    // ---- 8-way merge ----
    __syncthreads();   // everyone done with sP
    {
        float* ap = sMacc + (size_t)(w * 64 + lane) * MST;
        #pragma unroll
        for (int cb = 0; cb < 4; cb++) {
            *(f32x4*)(ap + cb * 4)      = acc0[cb];
            *(f32x4*)(ap + 16 + cb * 4) = acc1[cb];
        }
        if (g == 0) {
            float* p0 = sMml + (size_t)(w * 32 + li) * 2;
            p0[0] = m0; p0[1] = l0;
            float* p1 = sMml + (size_t)(w * 32 + 16 + li) * 2;
            p1[0] = m1; p1[1] = l1;
        }
    }
    __syncthreads();

    {
        // wave w merges channels [w*8, w*8+8) for all 32 rows
        const int r    = lane & 31;
        const int csub = lane >> 5;
        const int cq   = w * 2 + csub;       // channel quad (c = cq*4+e)
        const int g_s  = cq & 3;
        const int cb_s = cq >> 2;
        const int ib_s = r >> 4;
        const int li_s = r & 15;
        const int srcln = g_s * 16 + li_s;
        const int aidx  = ib_s * 16 + cb_s * 4;

        float mv[8], lv[8];
        #pragma unroll
        for (int w2 = 0; w2 < 8; w2++) {
            const float* mlp = sMml + (size_t)(w2 * 32 + r) * 2;
            mv[w2] = mlp[0]; lv[w2] = mlp[1];
        }
        float M = mv[0];
        #pragma unroll
        for (int w2 = 1; w2 < 8; w2++) M = fmaxf(M, mv[w2]);

        float num0 = 0.f, num1 = 0.f, num2 = 0.f, num3 = 0.f, L = 0.f;
        #pragma unroll
        for (int w2 = 0; w2 < 8; w2++) {
            const float s = __builtin_amdgcn_exp2f(mv[w2] - M);
            const f32x4 a = *(const f32x4*)(sMacc + (size_t)(w2 * 64 + srcln) * MST + aidx);
            num0 = fmaf(s, a[0], num0);
            num1 = fmaf(s, a[1], num1);
            num2 = fmaf(s, a[2], num2);
            num3 = fmaf(s, a[3], num3);
            L = fmaf(s, lv[w2], L);
        }
        const float inv = 1.0f / L;
        const float gmv = gamma[0];
        const size_t gb = (size_t)b * NC * NN + i0 + r;
        const size_t c0 = (size_t)(cq * 4);
        out[gb + (c0 + 0) * NN] = fmaf(gmv, num0 * inv, x[gb + (c0 + 0) * NN]);
        out[gb + (c0 + 1) * NN] = fmaf(gmv, num1 * inv, x[gb + (c0 + 1) * NN]);
        out[gb + (c0 + 2) * NN] = fmaf(gmv, num2 * inv, x[gb + (c0 + 2) * NN]);
        out[gb + (c0 + 3) * NN] = fmaf(gmv, num3 * inv, x[gb + (c0 + 3) * NN]);
    }
}

extern "C" void kernel_launch(void* const* d_in, const int* in_sizes, int n_in,
                              void* d_out, int out_size, void* d_ws, size_t ws_size,
                              hipStream_t stream) {
    const float* x     = (const float*)d_in[0];
    const float* Wq    = (const float*)d_in[1];
    const float* bq    = (const float*)d_in[2];
    const float* Wk    = (const float*)d_in[3];
    const float* bk    = (const float*)d_in[4];
    const float* Wv    = (const float*)d_in[5];
    const float* bv    = (const float*)d_in[6];
    const float* gamma = (const float*)d_in[7];
    float* out = (float*)d_out;

    // ws (ushorts): Q 8*32768 | K 8*32768 | V 8*131072  (3 MB total)
    ushort_t* Qws = (ushort_t*)d_ws;
    ushort_t* Kws = Qws + (size_t)NB * 32768;
    ushort_t* Vws = Kws + (size_t)NB * 32768;

    qkv_kernel<<<1280, 256, 0, stream>>>(x, Wq, bq, Wk, bk, Wv, bv, Qws, Kws, Vws);
    attn_kernel<<<512, 512, 0, stream>>>(Qws, Kws, Vws, x, gamma, out);
}